// Round 1
// baseline (6821.629 us; speedup 1.0000x reference)
//
#include <hip/hip_runtime.h>
#include <math.h>

// ---------------------------------------------------------------------------
// Problem constants (DeBERTa-style disentangled attention, B=2, S=2048)
// ---------------------------------------------------------------------------
#define NB     2
#define SEQ    2048
#define NHEAD  12
#define DHEAD  64
#define DMODEL 768
#define SPAN2  1024            // 2*ATT_SPAN
#define INFV   1e6f
// SCALE = 1/(sqrt(64)*sqrt(3)) = 1/sqrt(192); also the p2c kbn scale.
#define SCALEF 0.07216878364870323f

// ---------------------------------------------------------------------------
// Generic tiled f32 GEMM: out = (A @ W^T + b1 + b2) * scale, head-split layout
//   A: [R x 768] row-major, W: [768cols x 768] row-major
//   out[((batch*NHEAD + n) * rowsPerBatch + r%rpb) * 64 + d],  col c = n*64+d
// Grid: (R/64, 12), block 256 (16x16 threads, 4x4 microtile each)
// ---------------------------------------------------------------------------
__global__ __launch_bounds__(256) void gemm_headsplit(
    const float* __restrict__ A, const float* __restrict__ W,
    const float* __restrict__ b1, const float* __restrict__ b2,
    float scale, int rowsPerBatch, float* __restrict__ out)
{
    __shared__ float As[16][68];
    __shared__ float Ws[16][68];
    const int r0 = blockIdx.x * 64;
    const int n  = blockIdx.y;          // head index; c0 = n*64
    const int c0 = n * 64;
    const int tid = threadIdx.x;
    const int tx = tid & 15, ty = tid >> 4;

    float acc[4][4] = {};

    for (int k0 = 0; k0 < DMODEL; k0 += 16) {
        const int kk  = tid & 15;
        const int mm0 = tid >> 4;
        #pragma unroll
        for (int s = 0; s < 4; ++s) {
            const int mm = mm0 + s * 16;
            As[kk][mm] = A[(size_t)(r0 + mm) * DMODEL + k0 + kk];
            Ws[kk][mm] = W[(size_t)(c0 + mm) * DMODEL + k0 + kk];
        }
        __syncthreads();
        #pragma unroll
        for (int kk2 = 0; kk2 < 16; ++kk2) {
            float a[4], w[4];
            #pragma unroll
            for (int i = 0; i < 4; ++i) a[i] = As[kk2][ty * 4 + i];
            #pragma unroll
            for (int j = 0; j < 4; ++j) w[j] = Ws[kk2][tx * 4 + j];
            #pragma unroll
            for (int i = 0; i < 4; ++i)
                #pragma unroll
                for (int j = 0; j < 4; ++j)
                    acc[i][j] += a[i] * w[j];
        }
        __syncthreads();
    }

    #pragma unroll
    for (int i = 0; i < 4; ++i) {
        const int r  = r0 + ty * 4 + i;
        const int bb = r / rowsPerBatch;
        const int rr = r - bb * rowsPerBatch;
        #pragma unroll
        for (int j = 0; j < 4; ++j) {
            const int d = tx * 4 + j;
            const int c = c0 + d;
            float v = acc[i][j];
            if (b1) v += b1[c];
            if (b2) v += b2[c];
            v *= scale;
            out[(((size_t)bb * NHEAD + n) * rowsPerBatch + rr) * 64 + d] = v;
        }
    }
}

// ---------------------------------------------------------------------------
// Flash-style row-streaming attention with on-the-fly disentangled bias.
// Block = 256 threads = 4 waves, wave w handles row i = blockIdx.x*4 + w
// of head n = blockIdx.y, batch b = blockIdx.z.
// For each 64-wide j chunk, lane l computes the full score for j = j0+l:
//   score = q_i.k_j + [i>=1 && j>=1]*(q_i.pos_k[delta] + k_j.pos_q[delta])
//           - 1e6*(1-mask[b,j]),   delta = clip(i-j+512, 0, 1023)
// then online softmax + PV via a per-wave LDS prob buffer.
// ---------------------------------------------------------------------------
__global__ __launch_bounds__(256) void attention_kernel(
    const float* __restrict__ qh, const float* __restrict__ kh,
    const float* __restrict__ vh, const float* __restrict__ posk,
    const float* __restrict__ posq, const float* __restrict__ mask,
    float* __restrict__ attn)
{
    const int b  = blockIdx.z;
    const int n  = blockIdx.y;
    const int i0 = blockIdx.x * 4;
    const int tid  = threadIdx.x;
    const int w    = tid >> 6;
    const int lane = tid & 63;
    const int i    = i0 + w;
    const int bn   = b * NHEAD + n;

    __shared__ float qsh[4][64];
    __shared__ float pbuf[4][64];

    qsh[w][lane] = qh[((size_t)bn * SEQ + i) * 64 + lane];
    __syncthreads();

    float m = -1e30f, ssum = 0.f, outacc = 0.f;

    for (int j0 = 0; j0 < SEQ; j0 += 64) {
        const int j = j0 + lane;
        int delta = i - j + 512;
        delta = delta < 0 ? 0 : (delta > 1023 ? 1023 : delta);

        const float4* krow  = (const float4*)(kh   + ((size_t)bn * SEQ  + j)     * 64);
        const float4* pkrow = (const float4*)(posk + ((size_t)n * SPAN2 + delta) * 64);
        const float4* pqrow = (const float4*)(posq + ((size_t)n * SPAN2 + delta) * 64);
        const float4* qv4   = (const float4*)qsh[w];

        float ct = 0.f, cp = 0.f, pc = 0.f;
        #pragma unroll
        for (int d4 = 0; d4 < 16; ++d4) {
            const float4 kv  = krow[d4];
            const float4 pk4 = pkrow[d4];
            const float4 pq4 = pqrow[d4];
            const float4 qv  = qv4[d4];
            ct += qv.x * kv.x  + qv.y * kv.y  + qv.z * kv.z  + qv.w * kv.w;
            cp += qv.x * pk4.x + qv.y * pk4.y + qv.z * pk4.z + qv.w * pk4.w;
            pc += kv.x * pq4.x + kv.y * pq4.y + kv.z * pq4.z + kv.w * pq4.w;
        }

        const float bias  = (i >= 1 && j >= 1) ? (cp + pc) : 0.f;
        const float score = ct + bias - INFV * (1.f - mask[(size_t)b * SEQ + j]);

        // online softmax (wave-wide)
        float cm = score;
        #pragma unroll
        for (int off = 32; off; off >>= 1) cm = fmaxf(cm, __shfl_xor(cm, off));
        const float nm   = fmaxf(m, cm);
        const float corr = __expf(m - nm);
        const float p    = __expf(score - nm);
        float ps = p;
        #pragma unroll
        for (int off = 32; off; off >>= 1) ps += __shfl_xor(ps, off);
        ssum   = ssum * corr + ps;
        outacc = outacc * corr;
        m = nm;

        pbuf[w][lane] = p;
        __syncthreads();

        const float* vbase = vh + ((size_t)bn * SEQ + j0) * 64;
        #pragma unroll 8
        for (int jj = 0; jj < 64; ++jj) {
            outacc += pbuf[w][jj] * vbase[jj * 64 + lane];
        }
        __syncthreads();
    }

    attn[((size_t)b * SEQ + i) * DMODEL + n * 64 + lane] = outacc / ssum;
}

// ---------------------------------------------------------------------------
// Residual + LayerNorm, in-place on the attn buffer (reads row first).
// Block 256 per row (b,i); 768 = 3*256.
// ---------------------------------------------------------------------------
__global__ __launch_bounds__(256) void resid_ln(
    float* __restrict__ attn, const float* __restrict__ query,
    const float* __restrict__ gamma, const float* __restrict__ beta)
{
    const int b = blockIdx.y;
    const int i = blockIdx.x;
    const size_t base = ((size_t)b * SEQ + i) * DMODEL;
    const int tid = threadIdx.x;

    float x[3];
    #pragma unroll
    for (int s = 0; s < 3; ++s) x[s] = attn[base + s * 256 + tid];

    float sum = x[0] + x[1] + x[2];
    float sq  = x[0]*x[0] + x[1]*x[1] + x[2]*x[2];
    #pragma unroll
    for (int off = 32; off; off >>= 1) {
        sum += __shfl_xor(sum, off);
        sq  += __shfl_xor(sq, off);
    }
    __shared__ float red[2][4];
    const int w = tid >> 6;
    if ((tid & 63) == 0) { red[0][w] = sum; red[1][w] = sq; }
    __syncthreads();
    sum = red[0][0] + red[0][1] + red[0][2] + red[0][3];
    sq  = red[1][0] + red[1][1] + red[1][2] + red[1][3];

    const float mu  = sum * (1.f / DMODEL);
    const float var = sq * (1.f / DMODEL) - mu * mu;
    const float inv = rsqrtf(var + 1e-5f);

    #pragma unroll
    for (int s = 0; s < 3; ++s) {
        const int c = s * 256 + tid;
        attn[base + c] = query[base + c] + (x[s] - mu) * inv * gamma[c] + beta[c];
    }
}

// ---------------------------------------------------------------------------
extern "C" void kernel_launch(void* const* d_in, const int* in_sizes, int n_in,
                              void* d_out, int out_size, void* d_ws, size_t ws_size,
                              hipStream_t stream)
{
    const float* query = (const float*)d_in[0];
    const float* mask  = (const float*)d_in[1];
    const float* pke   = (const float*)d_in[2];
    const float* pqe   = (const float*)d_in[3];
    const float* Wq    = (const float*)d_in[4];
    const float* bq    = (const float*)d_in[5];
    const float* Wk    = (const float*)d_in[6];
    const float* Wv    = (const float*)d_in[7];
    const float* bv    = (const float*)d_in[8];
    const float* Wpq   = (const float*)d_in[9];
    const float* bpq   = (const float*)d_in[10];
    const float* Wpk   = (const float*)d_in[11];
    const float* rwb   = (const float*)d_in[12];  // r_w_bias [12][64] == per-col bias
    const float* gamma = (const float*)d_in[13];
    const float* beta  = (const float*)d_in[14];

    float* out = (float*)d_out;
    float* ws  = (float*)d_ws;

    const size_t QKV_ELEMS = (size_t)NB * NHEAD * SEQ * 64;   // 3,145,728
    const size_t POS_ELEMS = (size_t)NHEAD * SPAN2 * 64;      //   786,432

    float* qh   = ws;
    float* kh   = qh   + QKV_ELEMS;
    float* vh   = kh   + QKV_ELEMS;
    float* poskp = vh  + QKV_ELEMS;
    float* posqp = poskp + POS_ELEMS;

    dim3 blk(256);

    // projections (head-split layouts)
    gemm_headsplit<<<dim3(64, NHEAD), blk, 0, stream>>>(query, Wq, bq, rwb, SCALEF, SEQ, qh);
    gemm_headsplit<<<dim3(64, NHEAD), blk, 0, stream>>>(query, Wk, nullptr, nullptr, 1.f, SEQ, kh);
    gemm_headsplit<<<dim3(64, NHEAD), blk, 0, stream>>>(query, Wv, bv, nullptr, 1.f, SEQ, vh);
    gemm_headsplit<<<dim3(16, NHEAD), blk, 0, stream>>>(pke, Wpk, nullptr, nullptr, 1.f, SPAN2, poskp);
    gemm_headsplit<<<dim3(16, NHEAD), blk, 0, stream>>>(pqe, Wpq, bpq, nullptr, SCALEF, SPAN2, posqp);

    // attention -> d_out as [B,S,768] attn_vec
    attention_kernel<<<dim3(SEQ / 4, NHEAD, NB), blk, 0, stream>>>(
        qh, kh, vh, poskp, posqp, mask, out);

    // residual + LN in-place on d_out
    resid_ln<<<dim3(SEQ, NB), blk, 0, stream>>>(out, query, gamma, beta);
}

// Round 2
// 649.419 us; speedup vs baseline: 10.5042x; 10.5042x over previous
//
#include <hip/hip_runtime.h>
#include <math.h>

#define NB     2
#define SEQ    2048
#define NHEAD  12
#define DHEAD  64
#define DMODEL 768
#define SPAN2  1024
#define SCALEF 0.07216878364870323f   // 1/sqrt(192)

typedef unsigned short ushort;
typedef unsigned int   uint;
typedef __attribute__((ext_vector_type(8))) short bh8;    // 8 x bf16 (4 VGPR)
typedef __attribute__((ext_vector_type(4))) float f32x4;  // MFMA C/D frag

__device__ inline ushort f2bf(float x) {            // RNE f32 -> bf16
    uint u = __builtin_bit_cast(uint, x);
    u += 0x7FFFu + ((u >> 16) & 1u);
    return (ushort)(u >> 16);
}
__device__ inline float b2f(ushort h) {
    uint u = ((uint)h) << 16;
    return __builtin_bit_cast(float, u);
}

// ---------------------------------------------------------------------------
// f32 tiled GEMM (projections), bf16 output, head-split layout.
// out[((bb*NHEAD + n)*rowsPerBatch + rr)*64 + d],  col c = n*64+d
// ---------------------------------------------------------------------------
__global__ __launch_bounds__(256) void gemm_headsplit(
    const float* __restrict__ A, const float* __restrict__ W,
    const float* __restrict__ b1, const float* __restrict__ b2,
    float scale, int rowsPerBatch, ushort* __restrict__ out)
{
    __shared__ float As[16][68];
    __shared__ float Ws[16][68];
    const int r0 = blockIdx.x * 64;
    const int n  = blockIdx.y;
    const int c0 = n * 64;
    const int tid = threadIdx.x;
    const int tx = tid & 15, ty = tid >> 4;

    float acc[4][4] = {};

    for (int k0 = 0; k0 < DMODEL; k0 += 16) {
        const int kk  = tid & 15;
        const int mm0 = tid >> 4;
        #pragma unroll
        for (int s = 0; s < 4; ++s) {
            const int mm = mm0 + s * 16;
            As[kk][mm] = A[(size_t)(r0 + mm) * DMODEL + k0 + kk];
            Ws[kk][mm] = W[(size_t)(c0 + mm) * DMODEL + k0 + kk];
        }
        __syncthreads();
        #pragma unroll
        for (int kk2 = 0; kk2 < 16; ++kk2) {
            float a[4], w[4];
            #pragma unroll
            for (int i = 0; i < 4; ++i) a[i] = As[kk2][ty * 4 + i];
            #pragma unroll
            for (int j = 0; j < 4; ++j) w[j] = Ws[kk2][tx * 4 + j];
            #pragma unroll
            for (int i = 0; i < 4; ++i)
                #pragma unroll
                for (int j = 0; j < 4; ++j)
                    acc[i][j] += a[i] * w[j];
        }
        __syncthreads();
    }

    #pragma unroll
    for (int i = 0; i < 4; ++i) {
        const int r  = r0 + ty * 4 + i;
        const int bb = r / rowsPerBatch;
        const int rr = r - bb * rowsPerBatch;
        #pragma unroll
        for (int j = 0; j < 4; ++j) {
            const int d = tx * 4 + j;
            const int c = c0 + d;
            float v = acc[i][j];
            if (b1) v += b1[c];
            if (b2) v += b2[c];
            v *= scale;
            out[(((size_t)bb * NHEAD + n) * rowsPerBatch + rr) * 64 + d] = f2bf(v);
        }
    }
}

// ---------------------------------------------------------------------------
// MFMA flash attention with on-the-fly disentangled bias.
// Block: 256 thr = 4 waves; BM=64 rows (wave w owns rows w*16..w*16+15), BN=64.
// Per chunk: S = Q K^T (MFMA), T1 = Q pos_k_band^T, T2 = K pos_q_band^T (MFMA,
// band B-frags read from global), bias gather from T1/T2 LDS, online softmax
// on C-frag layout, PV via MFMA with V transposed in LDS.
// ---------------------------------------------------------------------------
__global__ __launch_bounds__(256) void attn_mfma(
    const ushort* __restrict__ qh, const ushort* __restrict__ kh,
    const ushort* __restrict__ vh, const ushort* __restrict__ posk,
    const ushort* __restrict__ posq, const float* __restrict__ mask,
    float* __restrict__ attn)
{
    // LDS: 52 KB static
    __shared__ ushort Ks [64 * 72];    // K chunk, padded rows (144B stride)
    __shared__ ushort Vts[64 * 72];    // V^T chunk: [d][j]
    __shared__ ushort T1s[64 * 136];   // T1 bf16 [i_loc][t]; later aliased as P
    __shared__ ushort T2s[64 * 136];   // T2 bf16 [j_loc][t]; head aliased as V staging

    const int b  = blockIdx.z;
    const int n  = blockIdx.y;
    const int i0 = blockIdx.x * 64;
    const int bn = b * NHEAD + n;
    const int tid  = threadIdx.x;
    const int w    = tid >> 6;
    const int lane = tid & 63;
    const int lo   = lane & 15;          // low 4 bits: M/N index of frags
    const int hi8  = (lane >> 4) * 8;    // K offset of A/B frags
    const int g4   = (lane >> 4) * 4;    // row group of C/D frags
    const int w16  = w * 16;

    // ---- hoist Q A-frags (rows w16+lo, k = hi8..hi8+7 and +32) ----
    const ushort* qbase = qh + ((size_t)bn * SEQ + i0 + w16 + lo) * 64;
    bh8 qa0 = *(const bh8*)&qbase[hi8];
    bh8 qa1 = *(const bh8*)&qbase[32 + hi8];

    f32x4 accPV[4] = {};                 // rows w16+g4+reg, cols dt*16+lo
    float mrow[4]  = {-1e30f, -1e30f, -1e30f, -1e30f};
    float lrow[4]  = {0.f, 0.f, 0.f, 0.f};

    const ushort* pkh = posk + (size_t)n * SPAN2 * 64;
    const ushort* pqh = posq + (size_t)n * SPAN2 * 64;

    for (int j0 = 0; j0 < SEQ; j0 += 64) {
        const int d0base = i0 - j0 + 449;      // delta0 = i0-j0+512-63

        // ---- stage1: K and V(linear, into T2s head) ----
        {
            const ushort* kg = kh + ((size_t)bn * SEQ + j0) * 64;
            const ushort* vg = vh + ((size_t)bn * SEQ + j0) * 64;
            #pragma unroll
            for (int p = 0; p < 2; ++p) {
                const int c = tid + p * 256;
                const int row = c >> 3, col = (c & 7) * 8;
                *(bh8*)&Ks [row * 72 + col] = *(const bh8*)&kg[c * 8];
                *(bh8*)&T2s[row * 72 + col] = *(const bh8*)&vg[c * 8];
            }
        }
        __syncthreads();   // B1

        // ---- stage2: transpose V into Vts[d][j] (conflict-free writes) ----
        {
            const int j = tid & 63;
            #pragma unroll
            for (int pass = 0; pass < 2; ++pass) {
                const int d0 = (tid >> 6) * 8 + pass * 32;
                bh8 v = *(const bh8*)&T2s[j * 72 + d0];
                #pragma unroll
                for (int e = 0; e < 8; ++e)
                    Vts[(d0 + e) * 72 + j] = ((ushort*)&v)[e];
            }
        }

        // ---- S = Q K^T : accS[ct] rows w16+g4+reg, cols ct*16+lo ----
        f32x4 accS[4];
        #pragma unroll
        for (int ct = 0; ct < 4; ++ct) {
            bh8 kb0 = *(const bh8*)&Ks[(ct * 16 + lo) * 72 + hi8];
            bh8 kb1 = *(const bh8*)&Ks[(ct * 16 + lo) * 72 + 32 + hi8];
            f32x4 z = {};
            z = __builtin_amdgcn_mfma_f32_16x16x32_bf16(qa0, kb0, z, 0, 0, 0);
            accS[ct] = __builtin_amdgcn_mfma_f32_16x16x32_bf16(qa1, kb1, z, 0, 0, 0);
        }

        // ---- T1 = Q pos_k_band^T -> T1s[i_loc][t] (bf16) ----
        #pragma unroll
        for (int tt = 0; tt < 8; ++tt) {
            int r = d0base + tt * 16 + lo;
            r = r < 0 ? 0 : (r > SPAN2 - 1 ? SPAN2 - 1 : r);
            const ushort* pb = pkh + (size_t)r * 64;
            bh8 b0 = *(const bh8*)&pb[hi8];
            bh8 b1 = *(const bh8*)&pb[32 + hi8];
            f32x4 z = {};
            z = __builtin_amdgcn_mfma_f32_16x16x32_bf16(qa0, b0, z, 0, 0, 0);
            z = __builtin_amdgcn_mfma_f32_16x16x32_bf16(qa1, b1, z, 0, 0, 0);
            #pragma unroll
            for (int reg = 0; reg < 4; ++reg)
                T1s[(w16 + g4 + reg) * 136 + tt * 16 + lo] = f2bf(z[reg]);
        }
        __syncthreads();   // B2: V staging reads done -> T2s writable

        // ---- T2 = K pos_q_band^T -> T2s[j_loc][t] (bf16) ----
        {
            bh8 ka0 = *(const bh8*)&Ks[(w16 + lo) * 72 + hi8];
            bh8 ka1 = *(const bh8*)&Ks[(w16 + lo) * 72 + 32 + hi8];
            #pragma unroll
            for (int tt = 0; tt < 8; ++tt) {
                int r = d0base + tt * 16 + lo;
                r = r < 0 ? 0 : (r > SPAN2 - 1 ? SPAN2 - 1 : r);
                const ushort* pb = pqh + (size_t)r * 64;
                bh8 b0 = *(const bh8*)&pb[hi8];
                bh8 b1 = *(const bh8*)&pb[32 + hi8];
                f32x4 z = {};
                z = __builtin_amdgcn_mfma_f32_16x16x32_bf16(ka0, b0, z, 0, 0, 0);
                z = __builtin_amdgcn_mfma_f32_16x16x32_bf16(ka1, b1, z, 0, 0, 0);
                #pragma unroll
                for (int reg = 0; reg < 4; ++reg)
                    T2s[(w16 + g4 + reg) * 136 + tt * 16 + lo] = f2bf(z[reg]);
            }
        }
        __syncthreads();   // B3: T1/T2 visible to all

        // ---- mask terms (4 j's per lane) ----
        float maskadd[4];
        #pragma unroll
        for (int ct = 0; ct < 4; ++ct)
            maskadd[ct] = -1e6f * (1.f - mask[(size_t)b * SEQ + j0 + ct * 16 + lo]);

        // ---- online softmax on frag layout; write P into T1s (alias) ----
        float corr[4];
        #pragma unroll
        for (int reg = 0; reg < 4; ++reg) {
            const int il = w16 + g4 + reg;
            const int gi = i0 + il;
            float s[4], rmax = -1e30f;
            #pragma unroll
            for (int ct = 0; ct < 4; ++ct) {
                const int jl = ct * 16 + lo;
                const int gj = j0 + jl;
                float v = accS[ct][reg];
                if (gi >= 1 && gj >= 1) {
                    const int t = il - jl + 63;
                    v += b2f(T1s[il * 136 + t]) + b2f(T2s[jl * 136 + t]);
                }
                v += maskadd[ct];
                s[ct] = v;
                rmax = fmaxf(rmax, v);
            }
            rmax = fmaxf(rmax, __shfl_xor(rmax, 1));
            rmax = fmaxf(rmax, __shfl_xor(rmax, 2));
            rmax = fmaxf(rmax, __shfl_xor(rmax, 4));
            rmax = fmaxf(rmax, __shfl_xor(rmax, 8));
            const float mnew = fmaxf(mrow[reg], rmax);
            const float c    = __expf(mrow[reg] - mnew);
            float psum = 0.f;
            #pragma unroll
            for (int ct = 0; ct < 4; ++ct) {
                const float p = __expf(s[ct] - mnew);
                psum += p;
                T1s[il * 136 + ct * 16 + lo] = f2bf(p);   // P[i_loc][j_loc]
            }
            psum += __shfl_xor(psum, 1);
            psum += __shfl_xor(psum, 2);
            psum += __shfl_xor(psum, 4);
            psum += __shfl_xor(psum, 8);
            lrow[reg] = lrow[reg] * c + psum;
            mrow[reg] = mnew;
            corr[reg] = c;
        }

        // ---- PV: acc = acc*corr + P V  (A = P rows of this wave, B = Vts) ----
        {
            bh8 pa0 = *(const bh8*)&T1s[(w16 + lo) * 136 + hi8];
            bh8 pa1 = *(const bh8*)&T1s[(w16 + lo) * 136 + 32 + hi8];
            #pragma unroll
            for (int dt = 0; dt < 4; ++dt) {
                bh8 vb0 = *(const bh8*)&Vts[(dt * 16 + lo) * 72 + hi8];
                bh8 vb1 = *(const bh8*)&Vts[(dt * 16 + lo) * 72 + 32 + hi8];
                f32x4 a = accPV[dt];
                #pragma unroll
                for (int reg = 0; reg < 4; ++reg) a[reg] *= corr[reg];
                a = __builtin_amdgcn_mfma_f32_16x16x32_bf16(pa0, vb0, a, 0, 0, 0);
                accPV[dt] = __builtin_amdgcn_mfma_f32_16x16x32_bf16(pa1, vb1, a, 0, 0, 0);
            }
        }
        __syncthreads();   // B4: protect Ks/Vts/T1s/T2s for next chunk
    }

    // ---- epilogue: divide by row sums, write attn_vec f32 ----
    #pragma unroll
    for (int reg = 0; reg < 4; ++reg) {
        const int i = i0 + w16 + g4 + reg;
        const float inv = 1.f / lrow[reg];
        #pragma unroll
        for (int dt = 0; dt < 4; ++dt)
            attn[((size_t)b * SEQ + i) * DMODEL + n * 64 + dt * 16 + lo] =
                accPV[dt][reg] * inv;
    }
}

// ---------------------------------------------------------------------------
// Residual + LayerNorm, in-place on attn buffer.
// ---------------------------------------------------------------------------
__global__ __launch_bounds__(256) void resid_ln(
    float* __restrict__ attn, const float* __restrict__ query,
    const float* __restrict__ gamma, const float* __restrict__ beta)
{
    const int b = blockIdx.y;
    const int i = blockIdx.x;
    const size_t base = ((size_t)b * SEQ + i) * DMODEL;
    const int tid = threadIdx.x;

    float x[3];
    #pragma unroll
    for (int s = 0; s < 3; ++s) x[s] = attn[base + s * 256 + tid];

    float sum = x[0] + x[1] + x[2];
    float sq  = x[0]*x[0] + x[1]*x[1] + x[2]*x[2];
    #pragma unroll
    for (int off = 32; off; off >>= 1) {
        sum += __shfl_xor(sum, off);
        sq  += __shfl_xor(sq, off);
    }
    __shared__ float red[2][4];
    const int w = tid >> 6;
    if ((tid & 63) == 0) { red[0][w] = sum; red[1][w] = sq; }
    __syncthreads();
    sum = red[0][0] + red[0][1] + red[0][2] + red[0][3];
    sq  = red[1][0] + red[1][1] + red[1][2] + red[1][3];

    const float mu  = sum * (1.f / DMODEL);
    const float var = sq * (1.f / DMODEL) - mu * mu;
    const float inv = rsqrtf(var + 1e-5f);

    #pragma unroll
    for (int s = 0; s < 3; ++s) {
        const int c = s * 256 + tid;
        attn[base + c] = query[base + c] + (x[s] - mu) * inv * gamma[c] + beta[c];
    }
}

// ---------------------------------------------------------------------------
extern "C" void kernel_launch(void* const* d_in, const int* in_sizes, int n_in,
                              void* d_out, int out_size, void* d_ws, size_t ws_size,
                              hipStream_t stream)
{
    const float* query = (const float*)d_in[0];
    const float* mask  = (const float*)d_in[1];
    const float* pke   = (const float*)d_in[2];
    const float* pqe   = (const float*)d_in[3];
    const float* Wq    = (const float*)d_in[4];
    const float* bq    = (const float*)d_in[5];
    const float* Wk    = (const float*)d_in[6];
    const float* Wv    = (const float*)d_in[7];
    const float* bv    = (const float*)d_in[8];
    const float* Wpq   = (const float*)d_in[9];
    const float* bpq   = (const float*)d_in[10];
    const float* Wpk   = (const float*)d_in[11];
    const float* rwb   = (const float*)d_in[12];
    const float* gamma = (const float*)d_in[13];
    const float* beta  = (const float*)d_in[14];

    float* out = (float*)d_out;

    const size_t QKV_ELEMS = (size_t)NB * NHEAD * SEQ * 64;   // 3,145,728
    const size_t POS_ELEMS = (size_t)NHEAD * SPAN2 * 64;      //   786,432

    ushort* qh   = (ushort*)d_ws;
    ushort* kh   = qh + QKV_ELEMS;
    ushort* vh   = kh + QKV_ELEMS;
    ushort* pkp  = vh + QKV_ELEMS;
    ushort* pqp  = pkp + POS_ELEMS;

    dim3 blk(256);

    gemm_headsplit<<<dim3(64, NHEAD), blk, 0, stream>>>(query, Wq, bq, rwb, SCALEF, SEQ, qh);
    gemm_headsplit<<<dim3(64, NHEAD), blk, 0, stream>>>(query, Wk, nullptr, nullptr, 1.f, SEQ, kh);
    gemm_headsplit<<<dim3(64, NHEAD), blk, 0, stream>>>(query, Wv, bv, nullptr, 1.f, SEQ, vh);
    gemm_headsplit<<<dim3(16, NHEAD), blk, 0, stream>>>(pke, Wpk, nullptr, nullptr, 1.f, SPAN2, pkp);
    gemm_headsplit<<<dim3(16, NHEAD), blk, 0, stream>>>(pqe, Wpq, bpq, nullptr, SCALEF, SPAN2, pqp);

    attn_mfma<<<dim3(SEQ / 64, NHEAD, NB), blk, 0, stream>>>(
        qh, kh, vh, pkp, pqp, mask, out);

    resid_ln<<<dim3(SEQ, NB), blk, 0, stream>>>(out, query, gamma, beta);
}

// Round 3
// 630.591 us; speedup vs baseline: 10.8178x; 1.0299x over previous
//
#include <hip/hip_runtime.h>
#include <math.h>

#define NB     2
#define SEQ    2048
#define NHEAD  12
#define DMODEL 768
#define SPAN2  1024
#define SCALEF 0.07216878364870323f   // 1/sqrt(192)

typedef unsigned short ushort;
typedef unsigned int   uint;
typedef __attribute__((ext_vector_type(8))) short  bh8;   // 8 x bf16
typedef __attribute__((ext_vector_type(4))) float  f32x4; // MFMA C/D frag
typedef __attribute__((ext_vector_type(4))) unsigned short us4;

__device__ inline ushort f2bf(float x) {            // RNE f32 -> bf16
    uint u = __builtin_bit_cast(uint, x);
    u += 0x7FFFu + ((u >> 16) & 1u);
    return (ushort)(u >> 16);
}
__device__ inline float b2f(ushort h) {
    uint u = ((uint)h) << 16;
    return __builtin_bit_cast(float, u);
}

// ---------------------------------------------------------------------------
// Multi-segment f32 -> bf16 convert. All n[] are multiples of 8.
// ---------------------------------------------------------------------------
struct CvtArgs {
    const float* src[8];
    ushort*      dst[8];
    int          n[8];
};

__global__ __launch_bounds__(256) void cvt_bf16(CvtArgs a)
{
    const int seg = blockIdx.y;
    const int i   = (blockIdx.x * 256 + threadIdx.x) * 8;
    if (i >= a.n[seg]) return;
    const float4* s = (const float4*)(a.src[seg] + i);
    const float4 x = s[0], y = s[1];
    bh8 o;
    o[0] = (short)f2bf(x.x); o[1] = (short)f2bf(x.y);
    o[2] = (short)f2bf(x.z); o[3] = (short)f2bf(x.w);
    o[4] = (short)f2bf(y.x); o[5] = (short)f2bf(y.y);
    o[6] = (short)f2bf(y.z); o[7] = (short)f2bf(y.w);
    *(bh8*)(a.dst[seg] + i) = o;
}

// ---------------------------------------------------------------------------
// LDS-free MFMA projection GEMM:  out = (X @ W^T + b1 + b2) * scale
//   X: [M x 768] bf16, W: [cols x 768] bf16 (row c = output col c).
//   Block = 64(M) x 64(N=head n) tile, 4 waves, each a 16x64 strip.
//   out  (head-split): out[((bb*12 + n)*rpb + rr)*64 + d]
//   outT (transposed): outT[((bb*12 + n)*64 + d)*rpb + rr]
// All operand fragments are contiguous 16B row slices (global, L2-hot).
// ---------------------------------------------------------------------------
__global__ __launch_bounds__(256) void proj_mfma(
    const ushort* __restrict__ X, const ushort* __restrict__ W,
    const float* __restrict__ b1, const float* __restrict__ b2,
    float scale, int rowsPerBatch,
    ushort* __restrict__ out, ushort* __restrict__ outT)
{
    const int r0 = blockIdx.x * 64;
    const int n  = blockIdx.y;
    const int c0 = n * 64;
    const int tid  = threadIdx.x;
    const int w    = tid >> 6;
    const int lane = tid & 63;
    const int lo   = lane & 15;
    const int hi8  = (lane >> 4) * 8;
    const int g4   = (lane >> 4) * 4;
    const int w16  = w * 16;

    const ushort* arow = X + (size_t)(r0 + w16 + lo) * DMODEL;

    f32x4 acc[4] = {};
    for (int k0 = 0; k0 < DMODEL; k0 += 64) {
        const bh8 a0 = *(const bh8*)&arow[k0 + hi8];
        const bh8 a1 = *(const bh8*)&arow[k0 + 32 + hi8];
        #pragma unroll
        for (int ct = 0; ct < 4; ++ct) {
            const ushort* wrow = W + (size_t)(c0 + ct * 16 + lo) * DMODEL + k0;
            const bh8 wb0 = *(const bh8*)&wrow[hi8];
            const bh8 wb1 = *(const bh8*)&wrow[32 + hi8];
            acc[ct] = __builtin_amdgcn_mfma_f32_16x16x32_bf16(a0, wb0, acc[ct], 0, 0, 0);
            acc[ct] = __builtin_amdgcn_mfma_f32_16x16x32_bf16(a1, wb1, acc[ct], 0, 0, 0);
        }
    }

    const int rbase = r0 + w16 + g4;                    // multiple of 4
    const int bb  = rbase / rowsPerBatch;
    const int rr0 = rbase - bb * rowsPerBatch;
    #pragma unroll
    for (int ct = 0; ct < 4; ++ct) {
        const int d = ct * 16 + lo;
        const int c = c0 + d;
        const float badd = (b1 ? b1[c] : 0.f) + (b2 ? b2[c] : 0.f);
        if (out) {
            #pragma unroll
            for (int reg = 0; reg < 4; ++reg)
                out[(((size_t)bb * NHEAD + n) * rowsPerBatch + rr0 + reg) * 64 + d] =
                    f2bf((acc[ct][reg] + badd) * scale);
        }
        if (outT) {
            us4 o;
            #pragma unroll
            for (int reg = 0; reg < 4; ++reg)
                o[reg] = f2bf((acc[ct][reg] + badd) * scale);
            *(us4*)&outT[(((size_t)bb * NHEAD + n) * 64 + d) * rowsPerBatch + rr0] = o;
        }
    }
}

// ---------------------------------------------------------------------------
// MFMA flash attention v2: all MFMA operands (Q/K rows, V^T rows, pos rows)
// are contiguous global row slices -> no K/V LDS staging, no V transpose.
// LDS holds only the bias band tables: T1 (wave-private, aliased by P) and
// T2 (cross-wave, double-buffered -> ONE barrier per chunk).
// ---------------------------------------------------------------------------
__global__ __launch_bounds__(256) void attn_mfma2(
    const ushort* __restrict__ qh, const ushort* __restrict__ kh,
    const ushort* __restrict__ vht, const ushort* __restrict__ posk,
    const ushort* __restrict__ posq, const float* __restrict__ mask,
    float* __restrict__ attn)
{
    __shared__ ushort T1s[64 * 132];       // T1 band [i_loc][t]; aliased as P
    __shared__ ushort T2s[2][64 * 132];    // T2 band [j_loc][t], double-buffered

    const int b  = blockIdx.z;
    const int n  = blockIdx.y;
    const int i0 = blockIdx.x * 64;
    const int bn = b * NHEAD + n;
    const int tid  = threadIdx.x;
    const int w    = tid >> 6;
    const int lane = tid & 63;
    const int lo   = lane & 15;
    const int hi8  = (lane >> 4) * 8;
    const int g4   = (lane >> 4) * 4;
    const int w16  = w * 16;

    const ushort* qrow = qh + ((size_t)bn * SEQ + i0 + w16 + lo) * 64;
    const bh8 qa0 = *(const bh8*)&qrow[hi8];
    const bh8 qa1 = *(const bh8*)&qrow[32 + hi8];

    const ushort* khb = kh  + (size_t)bn * SEQ * 64;
    const ushort* vtb = vht + (size_t)bn * 64 * SEQ;
    const ushort* pkh = posk + (size_t)n * SPAN2 * 64;
    const ushort* pqh = posq + (size_t)n * SPAN2 * 64;

    f32x4 accPV[4] = {};
    float mrow[4] = {-1e30f, -1e30f, -1e30f, -1e30f};
    float lrow[4] = {0.f, 0.f, 0.f, 0.f};

    for (int cix = 0; cix < SEQ / 64; ++cix) {
        const int j0 = cix * 64;
        const int d0base = i0 - j0 + 449;           // band row for t=0
        ushort* T2c = T2s[cix & 1];

        // ---- T2 = K_chunk · posq_band^T (this wave's 16 K rows) ----
        {
            const ushort* krA = khb + (size_t)(j0 + w16 + lo) * 64;
            const bh8 ka0 = *(const bh8*)&krA[hi8];
            const bh8 ka1 = *(const bh8*)&krA[32 + hi8];
            #pragma unroll
            for (int tt = 0; tt < 8; ++tt) {
                int r = d0base + tt * 16 + lo;
                r = r < 0 ? 0 : (r > SPAN2 - 1 ? SPAN2 - 1 : r);
                const ushort* pb = pqh + (size_t)r * 64;
                const bh8 b0 = *(const bh8*)&pb[hi8];
                const bh8 b1 = *(const bh8*)&pb[32 + hi8];
                f32x4 z = {};
                z = __builtin_amdgcn_mfma_f32_16x16x32_bf16(ka0, b0, z, 0, 0, 0);
                z = __builtin_amdgcn_mfma_f32_16x16x32_bf16(ka1, b1, z, 0, 0, 0);
                #pragma unroll
                for (int reg = 0; reg < 4; ++reg)
                    T2c[(w16 + g4 + reg) * 132 + tt * 16 + lo] = f2bf(z[reg]);
            }
        }

        // ---- S = Q K^T ----
        f32x4 accS[4];
        #pragma unroll
        for (int ct = 0; ct < 4; ++ct) {
            const ushort* kr = khb + (size_t)(j0 + ct * 16 + lo) * 64;
            const bh8 kb0 = *(const bh8*)&kr[hi8];
            const bh8 kb1 = *(const bh8*)&kr[32 + hi8];
            f32x4 z = {};
            z = __builtin_amdgcn_mfma_f32_16x16x32_bf16(qa0, kb0, z, 0, 0, 0);
            accS[ct] = __builtin_amdgcn_mfma_f32_16x16x32_bf16(qa1, kb1, z, 0, 0, 0);
        }

        // ---- T1 = Q · posk_band^T (own rows; no cross-wave access ever) ----
        #pragma unroll
        for (int tt = 0; tt < 8; ++tt) {
            int r = d0base + tt * 16 + lo;
            r = r < 0 ? 0 : (r > SPAN2 - 1 ? SPAN2 - 1 : r);
            const ushort* pb = pkh + (size_t)r * 64;
            const bh8 b0 = *(const bh8*)&pb[hi8];
            const bh8 b1 = *(const bh8*)&pb[32 + hi8];
            f32x4 z = {};
            z = __builtin_amdgcn_mfma_f32_16x16x32_bf16(qa0, b0, z, 0, 0, 0);
            z = __builtin_amdgcn_mfma_f32_16x16x32_bf16(qa1, b1, z, 0, 0, 0);
            #pragma unroll
            for (int reg = 0; reg < 4; ++reg)
                T1s[(w16 + g4 + reg) * 132 + tt * 16 + lo] = f2bf(z[reg]);
        }

        __syncthreads();    // T2c ready; prev-parity buffer free (double-buffer)

        float maskadd[4];
        #pragma unroll
        for (int ct = 0; ct < 4; ++ct)
            maskadd[ct] = -1e6f * (1.f - mask[(size_t)b * SEQ + j0 + ct * 16 + lo]);

        // ---- online softmax on C-frag layout; P overwrites T1 (reads-then-
        //      writes per row, wave-private rows => safe) ----
        float corr[4];
        #pragma unroll
        for (int reg = 0; reg < 4; ++reg) {
            const int il = w16 + g4 + reg;
            const int gi = i0 + il;
            float s[4], rmax = -1e30f;
            #pragma unroll
            for (int ct = 0; ct < 4; ++ct) {
                const int jl = ct * 16 + lo;
                const int gj = j0 + jl;
                float v = accS[ct][reg];
                if (gi >= 1 && gj >= 1) {
                    const int t = il - jl + 63;
                    v += b2f(T1s[il * 132 + t]) + b2f(T2c[jl * 132 + t]);
                }
                v += maskadd[ct];
                s[ct] = v;
                rmax = fmaxf(rmax, v);
            }
            rmax = fmaxf(rmax, __shfl_xor(rmax, 1));
            rmax = fmaxf(rmax, __shfl_xor(rmax, 2));
            rmax = fmaxf(rmax, __shfl_xor(rmax, 4));
            rmax = fmaxf(rmax, __shfl_xor(rmax, 8));
            const float mnew = fmaxf(mrow[reg], rmax);
            const float cc   = __expf(mrow[reg] - mnew);
            float psum = 0.f;
            #pragma unroll
            for (int ct = 0; ct < 4; ++ct) {
                const float p = __expf(s[ct] - mnew);
                psum += p;
                T1s[il * 132 + ct * 16 + lo] = f2bf(p);
            }
            psum += __shfl_xor(psum, 1);
            psum += __shfl_xor(psum, 2);
            psum += __shfl_xor(psum, 4);
            psum += __shfl_xor(psum, 8);
            lrow[reg] = lrow[reg] * cc + psum;
            mrow[reg] = mnew;
            corr[reg] = cc;
        }

        // ---- PV: A = P rows (LDS, own), B = V^T rows (global) ----
        {
            const bh8 pa0 = *(const bh8*)&T1s[(w16 + lo) * 132 + hi8];
            const bh8 pa1 = *(const bh8*)&T1s[(w16 + lo) * 132 + 32 + hi8];
            #pragma unroll
            for (int dt = 0; dt < 4; ++dt) {
                const ushort* vr = vtb + (size_t)(dt * 16 + lo) * SEQ + j0;
                const bh8 vb0 = *(const bh8*)&vr[hi8];
                const bh8 vb1 = *(const bh8*)&vr[32 + hi8];
                f32x4 a = accPV[dt];
                #pragma unroll
                for (int reg = 0; reg < 4; ++reg) a[reg] *= corr[reg];
                a = __builtin_amdgcn_mfma_f32_16x16x32_bf16(pa0, vb0, a, 0, 0, 0);
                accPV[dt] = __builtin_amdgcn_mfma_f32_16x16x32_bf16(pa1, vb1, a, 0, 0, 0);
            }
        }
        // no trailing barrier: T1s is wave-private, T2 parity alternates
    }

    #pragma unroll
    for (int reg = 0; reg < 4; ++reg) {
        const int i = i0 + w16 + g4 + reg;
        const float inv = 1.f / lrow[reg];
        #pragma unroll
        for (int dt = 0; dt < 4; ++dt)
            attn[((size_t)b * SEQ + i) * DMODEL + n * 64 + dt * 16 + lo] =
                accPV[dt][reg] * inv;
    }
}

// ---------------------------------------------------------------------------
// Residual + LayerNorm, in-place on attn buffer.
// ---------------------------------------------------------------------------
__global__ __launch_bounds__(256) void resid_ln(
    float* __restrict__ attn, const float* __restrict__ query,
    const float* __restrict__ gamma, const float* __restrict__ beta)
{
    const int b = blockIdx.y;
    const int i = blockIdx.x;
    const size_t base = ((size_t)b * SEQ + i) * DMODEL;
    const int tid = threadIdx.x;

    float x[3];
    #pragma unroll
    for (int s = 0; s < 3; ++s) x[s] = attn[base + s * 256 + tid];

    float sum = x[0] + x[1] + x[2];
    float sq  = x[0]*x[0] + x[1]*x[1] + x[2]*x[2];
    #pragma unroll
    for (int off = 32; off; off >>= 1) {
        sum += __shfl_xor(sum, off);
        sq  += __shfl_xor(sq, off);
    }
    __shared__ float red[2][4];
    const int w = tid >> 6;
    if ((tid & 63) == 0) { red[0][w] = sum; red[1][w] = sq; }
    __syncthreads();
    sum = red[0][0] + red[0][1] + red[0][2] + red[0][3];
    sq  = red[1][0] + red[1][1] + red[1][2] + red[1][3];

    const float mu  = sum * (1.f / DMODEL);
    const float var = sq * (1.f / DMODEL) - mu * mu;
    const float inv = rsqrtf(var + 1e-5f);

    #pragma unroll
    for (int s = 0; s < 3; ++s) {
        const int c = s * 256 + tid;
        attn[base + c] = query[base + c] + (x[s] - mu) * inv * gamma[c] + beta[c];
    }
}

// ---------------------------------------------------------------------------
extern "C" void kernel_launch(void* const* d_in, const int* in_sizes, int n_in,
                              void* d_out, int out_size, void* d_ws, size_t ws_size,
                              hipStream_t stream)
{
    const float* query = (const float*)d_in[0];
    const float* mask  = (const float*)d_in[1];
    const float* pke   = (const float*)d_in[2];
    const float* pqe   = (const float*)d_in[3];
    const float* Wq    = (const float*)d_in[4];
    const float* bq    = (const float*)d_in[5];
    const float* Wk    = (const float*)d_in[6];
    const float* Wv    = (const float*)d_in[7];
    const float* bv    = (const float*)d_in[8];
    const float* Wpq   = (const float*)d_in[9];
    const float* bpq   = (const float*)d_in[10];
    const float* Wpk   = (const float*)d_in[11];
    const float* rwb   = (const float*)d_in[12];
    const float* gamma = (const float*)d_in[13];
    const float* beta  = (const float*)d_in[14];

    float* out = (float*)d_out;

    const int Q_N  = NB * SEQ * DMODEL;        // 3,145,728
    const int P_N  = SPAN2 * DMODEL;           //   786,432
    const int W_N  = DMODEL * DMODEL;          //   589,824
    const size_t QKV_ELEMS = (size_t)NB * NHEAD * SEQ * 64;
    const size_t POS_ELEMS = (size_t)NHEAD * SPAN2 * 64;

    ushort* xb   = (ushort*)d_ws;
    ushort* pkeb = xb   + Q_N;
    ushort* pqeb = pkeb + P_N;
    ushort* wqb  = pqeb + P_N;
    ushort* wkb  = wqb  + W_N;
    ushort* wvb  = wkb  + W_N;
    ushort* wpqb = wvb  + W_N;
    ushort* wpkb = wpqb + W_N;
    ushort* qh   = wpkb + W_N;
    ushort* kh   = qh   + QKV_ELEMS;
    ushort* vht  = kh   + QKV_ELEMS;
    ushort* pkp  = vht  + QKV_ELEMS;
    ushort* pqp  = pkp  + POS_ELEMS;

    dim3 blk(256);

    CvtArgs ca;
    ca.src[0] = query; ca.dst[0] = xb;   ca.n[0] = Q_N;
    ca.src[1] = pke;   ca.dst[1] = pkeb; ca.n[1] = P_N;
    ca.src[2] = pqe;   ca.dst[2] = pqeb; ca.n[2] = P_N;
    ca.src[3] = Wq;    ca.dst[3] = wqb;  ca.n[3] = W_N;
    ca.src[4] = Wk;    ca.dst[4] = wkb;  ca.n[4] = W_N;
    ca.src[5] = Wv;    ca.dst[5] = wvb;  ca.n[5] = W_N;
    ca.src[6] = Wpq;   ca.dst[6] = wpqb; ca.n[6] = W_N;
    ca.src[7] = Wpk;   ca.dst[7] = wpkb; ca.n[7] = W_N;
    cvt_bf16<<<dim3((Q_N / 8 + 255) / 256, 8), blk, 0, stream>>>(ca);

    // projections
    proj_mfma<<<dim3(64, NHEAD), blk, 0, stream>>>(xb,   wqb,  bq,  rwb, SCALEF, SEQ,   qh,  nullptr);
    proj_mfma<<<dim3(64, NHEAD), blk, 0, stream>>>(xb,   wkb,  nullptr, nullptr, 1.f, SEQ, kh, nullptr);
    proj_mfma<<<dim3(64, NHEAD), blk, 0, stream>>>(xb,   wvb,  bv,  nullptr, 1.f,   SEQ,   nullptr, vht);
    proj_mfma<<<dim3(16, NHEAD), blk, 0, stream>>>(pkeb, wpkb, nullptr, nullptr, 1.f, SPAN2, pkp, nullptr);
    proj_mfma<<<dim3(16, NHEAD), blk, 0, stream>>>(pqeb, wpqb, bpq, nullptr, SCALEF, SPAN2, pqp, nullptr);

    // attention -> d_out as [B,S,768] attn_vec (f32)
    attn_mfma2<<<dim3(SEQ / 64, NHEAD, NB), blk, 0, stream>>>(
        qh, kh, vht, pkp, pqp, mask, out);

    // residual + LN in-place
    resid_ln<<<dim3(SEQ, NB), blk, 0, stream>>>(out, query, gamma, beta);
}